// Round 10
// baseline (177.863 us; speedup 1.0000x reference)
//
#include <hip/hip_runtime.h>
#include <hip/hip_bf16.h>

// Problem constants (fixed by the reference)
#define NROWS   200000
#define DSP     64      // spatial width
#define DST     131     // structural width
#define DSTP    136     // structural padded to 136 bf16 cols (272B rows, 16B-aligned)
#define DOUT    256
#define K1PAD   224     // 195 padded to 7*32
#define K2PAD   160     // 131 padded to 5*32
#define NK1     7
#define NK2     5
#define BM      64      // rows per block
#define NBLK    (NROWS / BM)   // 3125 exactly
#define LD1     (K1PAD + 8)    // 232 shorts = 464 B row stride
#define LD2     (K2PAD + 8)    // 168 shorts = 336 B row stride

typedef short bf8   __attribute__((ext_vector_type(8)));   // 8 bf16 (4 VGPRs)
typedef float f32x4 __attribute__((ext_vector_type(4)));
typedef float f4v   __attribute__((ext_vector_type(4)));   // for nontemporal builtins

// f32 -> bf16 (RNE) on raw bits (cold path / wprep only)
__device__ __forceinline__ unsigned short f2bf(float x) {
    unsigned u = __float_as_uint(x);
    unsigned r = (u + 0x7fffu + ((u >> 16) & 1u)) >> 16;
    return (unsigned short)r;
}

// hot path: HW bf16 convert
__device__ __forceinline__ unsigned short bf1(float x) {
    __hip_bfloat16 h = __float2bfloat16(x);
    return *reinterpret_cast<unsigned short*>(&h);
}
__device__ __forceinline__ unsigned packbf2(float a, float b) {
    return (unsigned)bf1(a) | ((unsigned)bf1(b) << 16);
}
// bf16 pair (packed in u32) -> two f32 (exact)
__device__ __forceinline__ float blo(unsigned u) { return __uint_as_float(u << 16); }
__device__ __forceinline__ float bhi(unsigned u) { return __uint_as_float(u & 0xffff0000u); }

// agg of 4 bf16x8 chunks: 0.25*(a+b+c+d), f32 arithmetic, repacked to bf16
__device__ __forceinline__ uint4 agg4(uint4 a, uint4 b, uint4 c, uint4 d) {
    uint4 r;
    #pragma unroll
    for (int i = 0; i < 4; ++i) {
        unsigned ua = (&a.x)[i], ub = (&b.x)[i];
        unsigned uc = (&c.x)[i], ud = (&d.x)[i];
        float lo = (blo(ua) + blo(ub)) + (blo(uc) + blo(ud));
        float hi = (bhi(ua) + bhi(ub)) + (bhi(uc) + bhi(ud));
        (&r.x)[i] = packbf2(lo * 0.25f, hi * 0.25f);
    }
    return r;
}

// ---------------------------------------------------------------------------
// Pack weights into MFMA B-fragment order:
//   entry(ks, cb, lane, j) = W[n][k], n = cb*16 + (lane&15), k = ks*32 + (lane>>4)*8 + j
// ---------------------------------------------------------------------------
__global__ __launch_bounds__(256) void wprep(const float* __restrict__ Wc,
                                             const float* __restrict__ Wa,
                                             short* __restrict__ w1p,
                                             short* __restrict__ w2p) {
    int idx = blockIdx.x * 256 + threadIdx.x;
    if (idx < 57344) {
        int j  = idx & 7;
        int l  = (idx >> 3) & 63;
        int cb = (idx >> 9) & 15;
        int ks = idx >> 13;
        int k  = ks * 32 + (l >> 4) * 8 + j;
        int n  = cb * 16 + (l & 15);
        float v = (k < 195) ? Wc[n * 195 + k] : 0.0f;
        w1p[idx] = (short)f2bf(v);
    } else {
        int id2 = idx - 57344;
        if (id2 < 40960) {
            int j  = id2 & 7;
            int l  = (id2 >> 3) & 63;
            int cb = (id2 >> 9) & 15;
            int ks = id2 >> 13;
            int k  = ks * 32 + (l >> 4) * 8 + j;
            int n  = cb * 16 + (l & 15);
            float v = (k < 131) ? Wa[n * 131 + k] : 0.0f;
            w2p[id2] = (short)f2bf(v);
        }
    }
}

// ---------------------------------------------------------------------------
// cvt: structural f32 [NROWS][131] -> sbf bf16 [NROWS][136] (cols 131..135 = 0)
// One row per half-wave. NT loads (f32 structural is single-use after this);
// NORMAL stores (sbf becomes the L3-resident gather working set).
// ---------------------------------------------------------------------------
__global__ __launch_bounds__(256) void cvt(const float* __restrict__ st,
                                           unsigned short* __restrict__ sbf) {
    int wid = (blockIdx.x * 256 + threadIdx.x) >> 6;
    int l   = threadIdx.x & 63;
    int h   = l >> 5, sub = l & 31;
    int nw  = (gridDim.x * 256) >> 6;
    for (int pr = wid; pr < NROWS / 2; pr += nw) {
        int row = pr * 2 + h;
        const float* src = st + (size_t)row * DST;
        unsigned short* dst = sbf + (size_t)row * DSTP;
        f4v v = __builtin_nontemporal_load((const f4v*)(src + 4 * sub));
        uint2 wv;
        wv.x = packbf2(v.x, v.y);
        wv.y = packbf2(v.z, v.w);
        *(uint2*)(dst + 4 * sub) = wv;
        if (sub == 0) {
            float4 tl = *(const float4*)(src + 127);   // cols 127..130 (4B-aligned, proven R5)
            uint4 tw;
            tw.x = packbf2(tl.y, tl.z);
            tw.y = packbf2(tl.w, 0.0f);
            tw.z = 0u;
            tw.w = 0u;
            *(uint4*)(dst + 128) = tw;
        }
    }
}

// ---------------------------------------------------------------------------
// MFMA core: LDS A-tile [BM][LDPAD] (bf16), fragment-packed B in wp,
// computes the BMx256 tile and stores f32 + bias via NON-TEMPORAL stores
// (no-allocate: keeps the streaming output from evicting the gather working
// set out of L2/L3 — confirmed -63us in R7).
// ---------------------------------------------------------------------------
template <int NK, int LDPAD, int MREP>
__device__ __forceinline__ void mfma_tile_and_store(
        const short (*lds)[LDPAD],
        const short* __restrict__ wp,
        const float* __restrict__ bias,
        float* __restrict__ out,
        int r0, int t) {
    const int wave = t >> 6;
    const int l    = t & 63;
    const int lr   = l & 15;   // A-row / D-col
    const int lk   = l >> 4;   // k-group / D-row-group

    f32x4 acc[MREP][4];
    #pragma unroll
    for (int m = 0; m < MREP; ++m)
        #pragma unroll
        for (int n = 0; n < 4; ++n)
            acc[m][n] = (f32x4){0.f, 0.f, 0.f, 0.f};

    #pragma unroll
    for (int ks = 0; ks < NK; ++ks) {
        bf8 a[MREP], bb[4];
        #pragma unroll
        for (int m = 0; m < MREP; ++m)
            a[m] = *(const bf8*)&lds[m * 16 + lr][ks * 32 + lk * 8];
        #pragma unroll
        for (int n = 0; n < 4; ++n) {
            int cb = wave * 4 + n;
            bb[n] = *(const bf8*)(wp + (((ks * 16 + cb) * 64 + l) << 3));
        }
        #pragma unroll
        for (int m = 0; m < MREP; ++m)
            #pragma unroll
            for (int n = 0; n < 4; ++n)
                acc[m][n] = __builtin_amdgcn_mfma_f32_16x16x32_bf16(
                                a[m], bb[n], acc[m][n], 0, 0, 0);
    }

    #pragma unroll
    for (int n = 0; n < 4; ++n) {
        int col = wave * 64 + n * 16 + lr;
        float bv = bias[col];
        #pragma unroll
        for (int m = 0; m < MREP; ++m) {
            #pragma unroll
            for (int r = 0; r < 4; ++r) {
                int row = m * 16 + lk * 4 + r;
                __builtin_nontemporal_store(
                    acc[m][n][r] + bv,
                    &out[(size_t)(r0 + row) * DOUT + col]);
            }
        }
    }
}

// ---------------------------------------------------------------------------
// Fused kernel, BM=64. All structural traffic is bf16 (sbf):
//  - gather: 16 lanes/row x 16B chunks (256B contiguous per pointer per pass);
//    self chunk copied to lds1 RAW; agg via agg4
//  - tail chunk (cols 128..135): shuffles hoisted OUT of the divergent branch
//    (exec-masked source lanes return 0 on CDNA ds_bpermute — R9 bug)
//  - NT: spatial loads, neigh loads, output stores; sbf loads cacheable
// ---------------------------------------------------------------------------
__global__ __launch_bounds__(256, 3) void fused(
        const float* __restrict__ spatial,
        const unsigned short* __restrict__ sbf,
        const int*   __restrict__ neigh,
        const short* __restrict__ w1p,
        const short* __restrict__ w2p,
        const float* __restrict__ b_comb,
        const float* __restrict__ b_agg,
        float* __restrict__ out1,
        float* __restrict__ out2) {
    __shared__ short lds1[BM][LD1];
    __shared__ short lds2[BM][LD2];
    const int t  = threadIdx.x;
    const int w  = t >> 6;
    const int l  = t & 63;
    const int r0 = blockIdx.x * BM;

    // ---- per-wave neigh preload: lanes 0..47 hold 16 rows x 3 indices ----
    int nv = 0;
    if (l < 48) {
        int lrow = l / 3;                 // 0..15 (local row)
        int lq   = l - lrow * 3;          // 0..2
        nv = __builtin_nontemporal_load(
                 neigh + (r0 + w * 16 + lrow) * 3 + lq);
    }

    // ---- zero pads (per-wave rows; written BEFORE the tail pass in wave
    //      program order, so tail data overwrites pad where they overlap) ----
    {
        int row = w * 16 + (l >> 2);
        int k   = l & 3;
        *(uint4*)&lds1[row][192 + 8 * k] = make_uint4(0, 0, 0, 0);  // cols 192..223
        *(uint4*)&lds2[row][128 + 8 * k] = make_uint4(0, 0, 0, 0);  // cols 128..159
    }

    // ---- stage spatial -> lds1 cols 0..63 (non-temporal float4 loads) ----
    {
        int h  = t & 15;
        int sl = t >> 4;
        #pragma unroll
        for (int p = 0; p < 4; ++p) {
            int row = sl + 16 * p;
            f4v v = __builtin_nontemporal_load(
                (const f4v*)(spatial + (size_t)(r0 + row) * DSP + 4 * h));
            uint2 wv;
            wv.x = packbf2(v.x, v.y);
            wv.y = packbf2(v.z, v.w);
            *(uint2*)&lds1[row][4 * h] = wv;
        }
    }

    // ---- gather staging from bf16 sbf rows (272B) ----
    {
        const char* sb = (const char*)sbf;
        const int c  = l & 15;            // 16B chunk (cols 8c..8c+7)
        const int rp = l >> 4;            // row-in-pass 0..3
        const unsigned co = 16u * (unsigned)c;
        #pragma unroll
        for (int p = 0; p < 4; ++p) {
            int local = p * 4 + rp;       // 0..15
            int row   = w * 16 + local;
            int srow  = r0 + row;
            int n0 = __shfl(nv, 3 * local + 0);
            int n1 = __shfl(nv, 3 * local + 1);
            int n2 = __shfl(nv, 3 * local + 2);
            uint4 s0 = *(const uint4*)(sb + (unsigned)srow * 272u + co);
            uint4 s1 = *(const uint4*)(sb + (unsigned)n0   * 272u + co);
            uint4 s2 = *(const uint4*)(sb + (unsigned)n1   * 272u + co);
            uint4 s3 = *(const uint4*)(sb + (unsigned)n2   * 272u + co);
            *(uint4*)&lds1[row][64 + 8 * c] = s0;            // raw bf16 copy
            *(uint4*)&lds2[row][8 * c]      = agg4(s0, s1, s2, s3);
        }
        // tail chunk: sbf cols 128..135 (131..135 are zeros from cvt).
        // Shuffles OUTSIDE the branch: all 64 lanes execute them so the
        // source lanes (0..47) are active (exec-masked sources return 0!).
        int tl_ = l & 15;
        int ti0 = __shfl(nv, 3 * tl_ + 0);
        int ti1 = __shfl(nv, 3 * tl_ + 1);
        int ti2 = __shfl(nv, 3 * tl_ + 2);
        if (l < 16) {
            int row  = w * 16 + l;
            int srow = r0 + row;
            uint4 s0 = *(const uint4*)(sb + (unsigned)srow * 272u + 256u);
            uint4 s1 = *(const uint4*)(sb + (unsigned)ti0  * 272u + 256u);
            uint4 s2 = *(const uint4*)(sb + (unsigned)ti1  * 272u + 256u);
            uint4 s3 = *(const uint4*)(sb + (unsigned)ti2  * 272u + 256u);
            *(uint4*)&lds1[row][192] = s0;                   // cols 192..199
            *(uint4*)&lds2[row][128] = agg4(s0, s1, s2, s3); // cols 128..135
        }
    }
    __syncthreads();

    mfma_tile_and_store<NK1, LD1, BM / 16>(lds1, w1p, b_comb, out1, r0, t);
    mfma_tile_and_store<NK2, LD2, BM / 16>(lds2, w2p, b_agg, out2, r0, t);
}

// ---------------------------------------------------------------------------
extern "C" void kernel_launch(void* const* d_in, const int* in_sizes, int n_in,
                              void* d_out, int out_size, void* d_ws, size_t ws_size,
                              hipStream_t stream) {
    const float* spatial    = (const float*)d_in[0];
    const float* structural = (const float*)d_in[1];
    const int*   neighbour  = (const int*)  d_in[2];
    const float* W_agg      = (const float*)d_in[3];
    const float* b_agg      = (const float*)d_in[4];
    const float* W_comb     = (const float*)d_in[5];
    const float* b_comb     = (const float*)d_in[6];

    float* out1 = (float*)d_out;
    float* out2 = out1 + (size_t)NROWS * DOUT;

    short* w1p = (short*)d_ws;                       // 57344 shorts
    short* w2p = w1p + 57344;                        // 40960 shorts
    unsigned short* sbf = (unsigned short*)((char*)d_ws + 196608);  // [NROWS][136] bf16

    wprep<<<384, 256, 0, stream>>>(W_comb, W_agg, w1p, w2p);
    cvt<<<2048, 256, 0, stream>>>(structural, sbf);
    fused<<<NBLK, 256, 0, stream>>>(spatial, sbf, neighbour,
                                    w1p, w2p, b_comb, b_agg, out1, out2);
}